// Round 10
// baseline (195.240 us; speedup 1.0000x reference)
//
#include <hip/hip_runtime.h>
#include <math.h>

#define D_INNER 5120
#define DT_RANK 160
#define N_STATE 16
#define BATCH   256
#define KTOT    192               // 160 (dt_low) | 16 (B) | 16 (C)

// ---- K1 config: 256-thr blocks, 4 waves x 40-dd chunks, intra-block reduce ----
#define BGRP    8                 // batches per block
#define NBG     (BATCH / BGRP)    // 32
#define DDBLK   160               // dd per block (4 waves x 40)
#define NDDB    (D_INNER / DDBLK) // 32 -> SPLIT partials
#define SPLIT   32

// ---- K3 config: FUSED, 4 batches/block, grid (20,64)=1280 blocks ----
#define K3_BT   4

// ---- workspace layout (float offsets) ----
#define OFF_T     0
#define SZ_T      (BATCH * KTOT)                  // 49,152
#define OFF_P     (OFF_T + SZ_T)
#define SZ_P      (SPLIT * BATCH * KTOT)          // 1,572,864 (6.3 MB)
#define OFF_SBC   (OFF_P + SZ_P)                  // sbc[b] = sum_n T[b][160+n]*T[b][176+n]

// ---------------------------------------------------------------------------
// K1: projection GEMM partials (unchanged, ~10 us).
// ---------------------------------------------------------------------------
__global__ __launch_bounds__(256) void k1_gemm(const float* __restrict__ x,
                                               const float* __restrict__ Wdtlow,
                                               const float* __restrict__ WB,
                                               const float* __restrict__ WC,
                                               float* __restrict__ ws) {
    __shared__ float lds[4 * BGRP * KTOT];   // 6144 floats = 24 KB
    const int tid  = threadIdx.x;
    const int lane = tid & 63;
    const int wv   = tid >> 6;               // wave 0..3
    const int b0   = blockIdx.x * BGRP;
    const int ddB  = blockIdx.y * DDBLK;

    float* xs = lds;
    for (int j = tid; j < (BGRP * DDBLK) / 4; j += 256) {   // 320 float4
        int i  = j / (DDBLK / 4);
        int c4 = j % (DDBLK / 4);
        float4 v = *(const float4*)(x + (size_t)(b0 + i) * D_INNER + ddB + c4 * 4);
        *(float4*)(xs + i * DDBLK + c4 * 4) = v;
    }
    __syncthreads();

    const int dd0 = wv * 40;
    const float* p0 = Wdtlow + (size_t)(ddB + dd0) * DT_RANK + lane;
    const float* p1 = p0 + 64;
    const float* p2;
    int st2;
    if (lane < 32)      { p2 = p0 + 128;                                          st2 = DT_RANK; }
    else if (lane < 48) { p2 = WB + (size_t)(ddB + dd0) * N_STATE + (lane - 32);  st2 = N_STATE; }
    else                { p2 = WC + (size_t)(ddB + dd0) * N_STATE + (lane - 48);  st2 = N_STATE; }

    float acc0[BGRP], acc1[BGRP], acc2[BGRP];
#pragma unroll
    for (int i = 0; i < BGRP; ++i) { acc0[i] = 0.f; acc1[i] = 0.f; acc2[i] = 0.f; }

#pragma unroll 2
    for (int g = 0; g < 10; ++g) {           // 4 dd per group
        float w0[4], w1[4], w2[4];
#pragma unroll
        for (int u = 0; u < 4; ++u) {
            int dd = g * 4 + u;
            w0[u] = p0[(size_t)dd * DT_RANK];
            w1[u] = p1[(size_t)dd * DT_RANK];
            w2[u] = p2[(size_t)dd * st2];
        }
#pragma unroll
        for (int i = 0; i < BGRP; ++i) {
            float4 xv = *(const float4*)(xs + i * DDBLK + dd0 + g * 4);
            acc0[i] += xv.x * w0[0] + xv.y * w0[1] + xv.z * w0[2] + xv.w * w0[3];
            acc1[i] += xv.x * w1[0] + xv.y * w1[1] + xv.z * w1[2] + xv.w * w1[3];
            acc2[i] += xv.x * w2[0] + xv.y * w2[1] + xv.z * w2[2] + xv.w * w2[3];
        }
    }
    __syncthreads();

#pragma unroll
    for (int i = 0; i < BGRP; ++i) {
        float* r = lds + wv * (BGRP * KTOT) + i * KTOT;
        r[lane]       = acc0[i];
        r[lane + 64]  = acc1[i];
        r[lane + 128] = acc2[i];
    }
    __syncthreads();

    float* P = ws + OFF_P + (size_t)blockIdx.y * (BATCH * KTOT) + (size_t)b0 * KTOT;
#pragma unroll
    for (int r = 0; r < 6; ++r) {
        int idx = tid + r * 256;
        P[idx] = lds[idx] + lds[idx + 1536] + lds[idx + 3072] + lds[idx + 4608];
    }
}

// ---------------------------------------------------------------------------
// K2: reduce split-K partials -> T[256][192], plus hoisted sbc[b]. (unchanged)
// ---------------------------------------------------------------------------
__global__ __launch_bounds__(192) void k2_reduce(float* __restrict__ ws) {
    __shared__ float ts[KTOT];
    const int b   = blockIdx.x;
    const int col = threadIdx.x;
    const float* P = ws + OFF_P + (size_t)b * KTOT + col;
    float a = 0.f;
#pragma unroll
    for (int s = 0; s < SPLIT; ++s) a += P[(size_t)s * (BATCH * KTOT)];
    ws[OFF_T + b * KTOT + col] = a;
    ts[col] = a;
    __syncthreads();
    if (col == 0) {
        float s2 = 0.f;
#pragma unroll
        for (int n = 0; n < N_STATE; ++n) s2 += ts[160 + n] * ts[176 + n];
        ws[OFF_SBC + b] = s2;
    }
}

// ---------------------------------------------------------------------------
// K3: FUSED delta GEMM + scan — h0 via global_load_lds (async DMA) round.
// Session facts: GEMM phase not the cost (r8); occupancy not the cost (r6);
// per-thread VGPR h0 prefetch impossible (r5/r6 sink, r7 spill). The scan's
// ~30us is exposed h0 latency with no legal register home. global_load_lds
// is the one mechanism with ZERO VGPR liveness (async DMA global->LDS, r8-
// proven mechanically in this kernel): the allocator cannot sink or spill it.
// This round applies it to the actual bottleneck operand:
//  * 16 DMA insts/thread stage the block's FULL h0 working set (4 batches x
//    256 d x 64B = 64KB) into LDS BEFORE the GEMM; the ~10us GEMM covers the
//    DMA flight; __syncthreads() (drains vmcnt, r8-verified) lands it.
//  * Scan reads h0 via ds_read_b128 (~12cy throughput) instead of 200-900cy
//    global latency. LDS layout == global layout (linear), standard b128
//    stride-16B pattern (same class as every GEMM LDA read).
//  * LDS 64KB/block -> 2 blocks/CU; r6 proved time is occupancy-insensitive;
//    MLP now lives in the DMA queue, not in wave count.
// GEMM + scan arithmetic: op-for-op round 4 (k-ascending, 4-partial y tree)
// -> numerics identical. Round-9 lane remap reverted (VALU redundancy).
// ---------------------------------------------------------------------------
__global__ __launch_bounds__(256) void k3_fused(const float* __restrict__ Wdt,
                                                const float* __restrict__ b_dt,
                                                const float* __restrict__ x,
                                                const float* __restrict__ A,
                                                const float* __restrict__ Dv,
                                                const float* __restrict__ h0,
                                                const float* __restrict__ ws,
                                                float* __restrict__ out) {
    __shared__ __align__(16) float ldsH[K3_BT * 256 * N_STATE];   // 64 KB
    const int tid  = threadIdx.x;
    const int lane = tid & 63;
    const int wv   = tid >> 6;                 // wave 0..3
    const int dblk = blockIdx.x * 256;
    const int d    = dblk + tid;
    const int b0   = blockIdx.y * K3_BT;
    const float* T  = ws + OFF_T;
    const float* SB = ws + OFF_SBC;

    // ---- issue the ENTIRE h0 working set as async DMA (no VGPR liveness) ----
    // Per (batch b, j): one wave-instruction stages 1KB. LDS dest is wave-
    // uniform (HW adds lane*16B); global src is per-lane linear -> coalesced.
    // LDS float index == within-block global float index (identical layout).
#pragma unroll
    for (int b = 0; b < K3_BT; ++b) {
#pragma unroll
        for (int j = 0; j < 4; ++j) {
            const float* s = h0 + ((size_t)(b0 + b) * D_INNER + dblk) * N_STATE
                           + wv * 1024 + j * 256 + lane * 4;
            float* dst = ldsH + b * 4096 + wv * 1024 + j * 256;   // uniform
            __builtin_amdgcn_global_load_lds(
                (const __attribute__((address_space(1))) void*)s,
                (__attribute__((address_space(3))) void*)dst,
                16, 0, 0);
        }
    }

    // ---- per-thread streaming loads (coalesced dwords) ----
    float xv[K3_BT];
#pragma unroll
    for (int i = 0; i < K3_BT; ++i) xv[i] = x[(size_t)(b0 + i) * D_INNER + d];

    const float bdt = b_dt[d];
    const float Dd  = Dv[d];
    const float4* a4 = (const float4*)(A + (size_t)d * N_STATE);
    float4 a0 = a4[0], a1 = a4[1], a2 = a4[2], a3 = a4[3];

    // ---- delta pre-activation GEMM (round-4 verbatim): DMA flies under it ----
    const float* tA = T + (size_t)b0 * KTOT;    // wave-uniform -> s_loads
    const float* tB = tA + KTOT;
    const float* tC = tB + KTOT;
    const float* tD = tC + KTOT;
    float acc[K3_BT] = {0.f, 0.f, 0.f, 0.f};
#pragma unroll 8
    for (int k = 0; k < DT_RANK; ++k) {
        float w = Wdt[(size_t)k * D_INNER + d];
        acc[0] += tA[k] * w;
        acc[1] += tB[k] * w;
        acc[2] += tC[k] * w;
        acc[3] += tD[k] * w;
    }

    __syncthreads();    // drains vmcnt (r8-verified): all h0 DMA has landed

    // ---- scan over 4 batches; h0 read from LDS (b128, ~12cy) ----
#pragma unroll
    for (int i = 0; i < K3_BT; ++i) {
        const int b = b0 + i;
        const float* Tb = T + (size_t)b * KTOT;       // uniform -> s_loads
        const float* hl = ldsH + i * 4096 + tid * 16;
        float4 hc0 = *(const float4*)(hl + 0);
        float4 hc1 = *(const float4*)(hl + 4);
        float4 hc2 = *(const float4*)(hl + 8);
        float4 hc3 = *(const float4*)(hl + 12);

        float v     = acc[i] + bdt;
        float delta = (v > 20.f) ? v : log1pf(__expf(v));
        float sbc   = SB[b];                          // hoisted to K2

        float y0, y1, y2, y3;                         // 4 partials: short chains
        y0  = __expf(delta * a0.x) * hc0.x * Tb[176 + 0];
        y0 += __expf(delta * a0.y) * hc0.y * Tb[176 + 1];
        y0 += __expf(delta * a0.z) * hc0.z * Tb[176 + 2];
        y0 += __expf(delta * a0.w) * hc0.w * Tb[176 + 3];
        y1  = __expf(delta * a1.x) * hc1.x * Tb[176 + 4];
        y1 += __expf(delta * a1.y) * hc1.y * Tb[176 + 5];
        y1 += __expf(delta * a1.z) * hc1.z * Tb[176 + 6];
        y1 += __expf(delta * a1.w) * hc1.w * Tb[176 + 7];
        y2  = __expf(delta * a2.x) * hc2.x * Tb[176 + 8];
        y2 += __expf(delta * a2.y) * hc2.y * Tb[176 + 9];
        y2 += __expf(delta * a2.z) * hc2.z * Tb[176 + 10];
        y2 += __expf(delta * a2.w) * hc2.w * Tb[176 + 11];
        y3  = __expf(delta * a3.x) * hc3.x * Tb[176 + 12];
        y3 += __expf(delta * a3.y) * hc3.y * Tb[176 + 13];
        y3 += __expf(delta * a3.z) * hc3.z * Tb[176 + 14];
        y3 += __expf(delta * a3.w) * hc3.w * Tb[176 + 15];

        out[(size_t)b * D_INNER + d] = xv[i] * (Dd + delta * sbc)
                                     + ((y0 + y1) + (y2 + y3));
    }
}

// ---------------------------------------------------------------------------
extern "C" void kernel_launch(void* const* d_in, const int* in_sizes, int n_in,
                              void* d_out, int out_size, void* d_ws, size_t ws_size,
                              hipStream_t stream) {
    const float* x      = (const float*)d_in[0];
    const float* Wdtlow = (const float*)d_in[1];
    const float* Wdt    = (const float*)d_in[2];
    const float* bdt    = (const float*)d_in[3];
    const float* WB     = (const float*)d_in[4];
    const float* WC     = (const float*)d_in[5];
    const float* A      = (const float*)d_in[6];
    const float* Dv     = (const float*)d_in[7];
    const float* h0     = (const float*)d_in[8];
    float* ws  = (float*)d_ws;
    float* out = (float*)d_out;

    // K1: projection GEMM partials (1024 blocks, unchanged)
    hipLaunchKernelGGL(k1_gemm, dim3(NBG, NDDB), dim3(256), 0, stream,
                       x, Wdtlow, WB, WC, ws);
    // K2: reduce partials -> T[256][192] + sbc[256]
    hipLaunchKernelGGL(k2_reduce, dim3(BATCH), dim3(192), 0, stream, ws);
    // K3: fused delta GEMM + scan, h0 DMA-staged in LDS, grid (20,64)
    hipLaunchKernelGGL(k3_fused, dim3(D_INNER / 256, BATCH / K3_BT), dim3(256),
                       0, stream, Wdt, bdt, x, A, Dv, h0, ws, out);
}

// Round 11
// 173.772 us; speedup vs baseline: 1.1235x; 1.1235x over previous
//
#include <hip/hip_runtime.h>
#include <math.h>

#define D_INNER 5120
#define DT_RANK 160
#define N_STATE 16
#define BATCH   256
#define KTOT    192               // 160 (dt_low) | 16 (B) | 16 (C)

// ---- K1 config: 256-thr blocks, 4 waves x 40-dd chunks, intra-block reduce ----
#define BGRP    8                 // batches per block
#define NBG     (BATCH / BGRP)    // 32
#define DDBLK   160               // dd per block (4 waves x 40)
#define NDDB    (D_INNER / DDBLK) // 32 -> SPLIT partials
#define SPLIT   32

// ---- K3 config: FUSED, 4 batches/block, grid (20,64)=1280 blocks ----
#define K3_BT   4

// ---- workspace layout (float offsets) ----
#define OFF_T     0
#define SZ_T      (BATCH * KTOT)                  // 49,152
#define OFF_P     (OFF_T + SZ_T)
#define SZ_P      (SPLIT * BATCH * KTOT)          // 1,572,864 (6.3 MB)
#define OFF_SBC   (OFF_P + SZ_P)                  // sbc[b] = sum_n T[b][160+n]*T[b][176+n]

// ---------------------------------------------------------------------------
// K1: projection GEMM partials (unchanged, ~10 us).
// ---------------------------------------------------------------------------
__global__ __launch_bounds__(256) void k1_gemm(const float* __restrict__ x,
                                               const float* __restrict__ Wdtlow,
                                               const float* __restrict__ WB,
                                               const float* __restrict__ WC,
                                               float* __restrict__ ws) {
    __shared__ float lds[4 * BGRP * KTOT];   // 6144 floats = 24 KB
    const int tid  = threadIdx.x;
    const int lane = tid & 63;
    const int wv   = tid >> 6;               // wave 0..3
    const int b0   = blockIdx.x * BGRP;
    const int ddB  = blockIdx.y * DDBLK;

    float* xs = lds;
    for (int j = tid; j < (BGRP * DDBLK) / 4; j += 256) {   // 320 float4
        int i  = j / (DDBLK / 4);
        int c4 = j % (DDBLK / 4);
        float4 v = *(const float4*)(x + (size_t)(b0 + i) * D_INNER + ddB + c4 * 4);
        *(float4*)(xs + i * DDBLK + c4 * 4) = v;
    }
    __syncthreads();

    const int dd0 = wv * 40;
    const float* p0 = Wdtlow + (size_t)(ddB + dd0) * DT_RANK + lane;
    const float* p1 = p0 + 64;
    const float* p2;
    int st2;
    if (lane < 32)      { p2 = p0 + 128;                                          st2 = DT_RANK; }
    else if (lane < 48) { p2 = WB + (size_t)(ddB + dd0) * N_STATE + (lane - 32);  st2 = N_STATE; }
    else                { p2 = WC + (size_t)(ddB + dd0) * N_STATE + (lane - 48);  st2 = N_STATE; }

    float acc0[BGRP], acc1[BGRP], acc2[BGRP];
#pragma unroll
    for (int i = 0; i < BGRP; ++i) { acc0[i] = 0.f; acc1[i] = 0.f; acc2[i] = 0.f; }

#pragma unroll 2
    for (int g = 0; g < 10; ++g) {           // 4 dd per group
        float w0[4], w1[4], w2[4];
#pragma unroll
        for (int u = 0; u < 4; ++u) {
            int dd = g * 4 + u;
            w0[u] = p0[(size_t)dd * DT_RANK];
            w1[u] = p1[(size_t)dd * DT_RANK];
            w2[u] = p2[(size_t)dd * st2];
        }
#pragma unroll
        for (int i = 0; i < BGRP; ++i) {
            float4 xv = *(const float4*)(xs + i * DDBLK + dd0 + g * 4);
            acc0[i] += xv.x * w0[0] + xv.y * w0[1] + xv.z * w0[2] + xv.w * w0[3];
            acc1[i] += xv.x * w1[0] + xv.y * w1[1] + xv.z * w1[2] + xv.w * w1[3];
            acc2[i] += xv.x * w2[0] + xv.y * w2[1] + xv.z * w2[2] + xv.w * w2[3];
        }
    }
    __syncthreads();

#pragma unroll
    for (int i = 0; i < BGRP; ++i) {
        float* r = lds + wv * (BGRP * KTOT) + i * KTOT;
        r[lane]       = acc0[i];
        r[lane + 64]  = acc1[i];
        r[lane + 128] = acc2[i];
    }
    __syncthreads();

    float* P = ws + OFF_P + (size_t)blockIdx.y * (BATCH * KTOT) + (size_t)b0 * KTOT;
#pragma unroll
    for (int r = 0; r < 6; ++r) {
        int idx = tid + r * 256;
        P[idx] = lds[idx] + lds[idx + 1536] + lds[idx + 3072] + lds[idx + 4608];
    }
}

// ---------------------------------------------------------------------------
// K2: reduce split-K partials -> T[256][192], plus hoisted sbc[b]. (unchanged)
// ---------------------------------------------------------------------------
__global__ __launch_bounds__(192) void k2_reduce(float* __restrict__ ws) {
    __shared__ float ts[KTOT];
    const int b   = blockIdx.x;
    const int col = threadIdx.x;
    const float* P = ws + OFF_P + (size_t)b * KTOT + col;
    float a = 0.f;
#pragma unroll
    for (int s = 0; s < SPLIT; ++s) a += P[(size_t)s * (BATCH * KTOT)];
    ws[OFF_T + b * KTOT + col] = a;
    ts[col] = a;
    __syncthreads();
    if (col == 0) {
        float s2 = 0.f;
#pragma unroll
        for (int n = 0; n < N_STATE; ++n) s2 += ts[160 + n] * ts[176 + n];
        ws[OFF_SBC + b] = s2;
    }
}

// ---------------------------------------------------------------------------
// K3: FUSED delta GEMM + softplus + scan — round-4 kernel VERBATIM (best
// measured: 173.1us total, K3~41.5us) + ONE change: T1-style XCD work
// permutation (pure index remap; zero numeric/register risk).
// Theory (counter-grounded): Wdt's 1.3MB slice is reused by 64 blocks that
// are 20 apart in linear dispatch id (x-fastest) -> temporally spread across
// the whole kernel while 84MB of h0 streams through the same L2s; and with
// XCD=id%8 each XCD touches ~5 slices (6.5MB > 4MB L2). The slice cannot
// stay L2-resident -> the GEMM's 160 loads/thread run at L3 latency
// (~400-600cy), not the assumed L2-hit. That is the exposed-latency gap that
// occupancy (r6), prefetch (r5-r7), and staging (r8) all failed to close.
// Fix: hwid = x + 20y; xcd = hwid%8; rank = hwid/8; w = xcd*160 + rank;
// work = (bx,by) = (w/64, w%64). Bijective (1280 = 8*160 = 20*64). Each XCD
// covers <=3 slices (3.9MB, fits L2) and the 64 reusers of a slice launch
// back-to-back (temporal locality).
// ---------------------------------------------------------------------------
__global__ __launch_bounds__(256, 5) void k3_fused(const float* __restrict__ Wdt,
                                                   const float* __restrict__ b_dt,
                                                   const float* __restrict__ x,
                                                   const float* __restrict__ A,
                                                   const float* __restrict__ Dv,
                                                   const float* __restrict__ h0,
                                                   const float* __restrict__ ws,
                                                   float* __restrict__ out) {
    const int tid  = threadIdx.x;
    // ---- XCD work permutation (see header comment) ----
    const int hwid = blockIdx.x + 20 * blockIdx.y;   // linear dispatch id
    const int xcd  = hwid & 7;                        // round-robin XCD
    const int rank = hwid >> 3;                       // [0,160)
    const int w    = xcd * 160 + rank;                // contiguous chunk/XCD
    const int bx   = w >> 6;                          // work d-block  [0,20)
    const int by   = w & 63;                          // work batch-grp [0,64)

    const int d   = bx * 256 + tid;
    const int b0  = by * K3_BT;
    const float* T  = ws + OFF_T;
    const float* SB = ws + OFF_SBC;

    // ---- issue long-latency HBM loads FIRST: h0 batches 0,1 + x[0..3] ----
    const float4* hb = (const float4*)(h0 + ((size_t)b0 * D_INNER + d) * N_STATE);
    const size_t  hstride = (size_t)D_INNER * 4;     // float4s per batch step

    float4 hc0 = hb[0], hc1 = hb[1], hc2 = hb[2], hc3 = hb[3];
    const float4* h1p = hb + hstride;
    float4 hn0 = h1p[0], hn1 = h1p[1], hn2 = h1p[2], hn3 = h1p[3];

    float xv[K3_BT];
#pragma unroll
    for (int i = 0; i < K3_BT; ++i) xv[i] = x[(size_t)(b0 + i) * D_INNER + d];

    const float bdt = b_dt[d];
    const float Dd  = Dv[d];
    const float4* a4 = (const float4*)(A + (size_t)d * N_STATE);
    float4 a0 = a4[0], a1 = a4[1], a2 = a4[2], a3 = a4[3];

    // ---- delta pre-activation GEMM: acc[i] = T[b0+i][0..159] . Wdt[:,d] ----
    // T rows wave-uniform -> s_loads; Wdt k-major coalesced (1KB/wave/k).
    float acc[K3_BT] = {0.f, 0.f, 0.f, 0.f};
#pragma unroll 8
    for (int k = 0; k < DT_RANK; ++k) {
        float w_ = Wdt[(size_t)k * D_INNER + d];
#pragma unroll
        for (int i = 0; i < K3_BT; ++i)
            acc[i] += T[(size_t)(b0 + i) * KTOT + k] * w_;
    }

    // ---- scan over 4 batches, 2-deep h0 prefetch (round-4 verbatim) ----
#pragma unroll
    for (int i = 0; i < K3_BT; ++i) {
        float4 p0, p1, p2, p3;
        if (i + 2 < K3_BT) {                          // prefetch batch i+2
            const float4* hp = hb + (size_t)(i + 2) * hstride;
            p0 = hp[0]; p1 = hp[1]; p2 = hp[2]; p3 = hp[3];
        }

        const int b = b0 + i;
        const float* Tb = T + (size_t)b * KTOT;       // uniform -> s_loads

        float v     = acc[i] + bdt;
        float delta = (v > 20.f) ? v : log1pf(__expf(v));
        float sbc   = SB[b];                          // hoisted to K2

        float y0, y1, y2, y3;                         // 4 partials: short chains
        y0  = __expf(delta * a0.x) * hc0.x * Tb[176 + 0];
        y0 += __expf(delta * a0.y) * hc0.y * Tb[176 + 1];
        y0 += __expf(delta * a0.z) * hc0.z * Tb[176 + 2];
        y0 += __expf(delta * a0.w) * hc0.w * Tb[176 + 3];
        y1  = __expf(delta * a1.x) * hc1.x * Tb[176 + 4];
        y1 += __expf(delta * a1.y) * hc1.y * Tb[176 + 5];
        y1 += __expf(delta * a1.z) * hc1.z * Tb[176 + 6];
        y1 += __expf(delta * a1.w) * hc1.w * Tb[176 + 7];
        y2  = __expf(delta * a2.x) * hc2.x * Tb[176 + 8];
        y2 += __expf(delta * a2.y) * hc2.y * Tb[176 + 9];
        y2 += __expf(delta * a2.z) * hc2.z * Tb[176 + 10];
        y2 += __expf(delta * a2.w) * hc2.w * Tb[176 + 11];
        y3  = __expf(delta * a3.x) * hc3.x * Tb[176 + 12];
        y3 += __expf(delta * a3.y) * hc3.y * Tb[176 + 13];
        y3 += __expf(delta * a3.z) * hc3.z * Tb[176 + 14];
        y3 += __expf(delta * a3.w) * hc3.w * Tb[176 + 15];

        out[(size_t)b * D_INNER + d] = xv[i] * (Dd + delta * sbc)
                                     + ((y0 + y1) + (y2 + y3));

        if (i < K3_BT - 1) { hc0 = hn0; hc1 = hn1; hc2 = hn2; hc3 = hn3; }
        if (i + 2 < K3_BT) { hn0 = p0;  hn1 = p1;  hn2 = p2;  hn3 = p3;  }
    }
}

// ---------------------------------------------------------------------------
extern "C" void kernel_launch(void* const* d_in, const int* in_sizes, int n_in,
                              void* d_out, int out_size, void* d_ws, size_t ws_size,
                              hipStream_t stream) {
    const float* x      = (const float*)d_in[0];
    const float* Wdtlow = (const float*)d_in[1];
    const float* Wdt    = (const float*)d_in[2];
    const float* bdt    = (const float*)d_in[3];
    const float* WB     = (const float*)d_in[4];
    const float* WC     = (const float*)d_in[5];
    const float* A      = (const float*)d_in[6];
    const float* Dv     = (const float*)d_in[7];
    const float* h0     = (const float*)d_in[8];
    float* ws  = (float*)d_ws;
    float* out = (float*)d_out;

    // K1: projection GEMM partials (1024 blocks, unchanged)
    hipLaunchKernelGGL(k1_gemm, dim3(NBG, NDDB), dim3(256), 0, stream,
                       x, Wdtlow, WB, WC, ws);
    // K2: reduce partials -> T[256][192] + sbc[256]
    hipLaunchKernelGGL(k2_reduce, dim3(BATCH), dim3(192), 0, stream, ws);
    // K3: fused delta GEMM + scan, BT=4, grid (20,64)=1280, XCD-swizzled
    hipLaunchKernelGGL(k3_fused, dim3(D_INNER / 256, BATCH / K3_BT), dim3(256),
                       0, stream, Wdt, bdt, x, A, Dv, h0, ws, out);
}